// Round 11
// baseline (98.913 us; speedup 1.0000x reference)
//
#include <hip/hip_runtime.h>

#define AHH 7
#define AWW 7
#define NS 49            // AH*AW
#define CC 256
#define HH 64
#define WW 64
#define CCH 64                            // channels per block chunk
#define NCHUNK (CC / CCH)                 // 4 blocks per roi
#define ELEMS_PER_ROI (CC * NS)           // 12544
#define RSTRIDE 53                        // LDS row stride (words): ≡1 mod 4
#define FT_ELEMS (2 * HH * WW * CC)       // 8 MiB
#define TS 64                             // transpose tile
#define WCH 16                            // channels per wave
#define VEC4_PER_WAVE (WCH * NS / 4)      // 196

typedef float v4f __attribute__((ext_vector_type(4)));

// ---------------- tiled transpose (B,C,HW) -> (B,HW,C) ----------------
__global__ __launch_bounds__(256) void transpose_tiled(
    const float* __restrict__ A, float* __restrict__ AT) {
  const int bid = blockIdx.x;            // 512 blocks
  const int st  = bid & 63;              // spatial tile (4096/64)
  const int ct  = (bid >> 6) & 3;        // channel tile (256/64)
  const int b   = bid >> 8;
  const int tid = threadIdx.x;

  __shared__ float tile[TS][TS + 1];

  const float* Ab  = A  + (size_t)b * CC * HH * WW;
  float*       ATb = AT + (size_t)b * HH * WW * CC;

  {
    const int col = tid & 63;
    const int r0  = tid >> 6;            // 0..3
#pragma unroll
    for (int k = 0; k < 16; ++k) {
      int r = r0 + (k << 2);
      tile[r][col] = Ab[(size_t)(ct * TS + r) * (HH * WW) + st * TS + col];
    }
  }
  __syncthreads();
  {
    const int col4 = (tid & 15) << 2;    // 4 consecutive channels
    const int rr   = tid >> 4;           // 0..15
#pragma unroll
    for (int k = 0; k < 4; ++k) {
      int r = rr + (k << 4);
      v4f val = {tile[col4][r], tile[col4 + 1][r], tile[col4 + 2][r], tile[col4 + 3][r]};
      *(v4f*)(ATb + (size_t)(st * TS + r) * CC + ct * TS + col4) = val;
    }
  }
}

// ---------------- main: 4 blocks/roi, wave-private 16-channel epilogue ----------------
__global__ __launch_bounds__(256) void roialign_t_kernel(
    const float* __restrict__ fT,
    const float* __restrict__ rois,
    float* __restrict__ out) {
  const int bid   = blockIdx.x;
  const int n     = bid >> 2;            // roi index
  const int chunk = bid & 3;             // channel chunk 0..3
  const int c0    = chunk * CCH;
  const int tid   = threadIdx.x;
  const int wv    = tid >> 6;            // wave 0..3 (owns channels 16*wv .. +15)
  const int lane  = tid & 63;

  __shared__ float s_w[4][NS];
  __shared__ int   s_poff[NS];           // (h0*W + w0) * C
  __shared__ int   s_base;               // b * H*W*C
  __shared__ float s_res[CCH * RSTRIDE]; // 13.25 KB; wave w owns rows 16w..16w+15

  if (tid < NS) {
    const float* roi = rois + n * 5;
    float bf = roi[0];
    float x1 = roi[1] * 0.0625f;
    float y1 = roi[2] * 0.0625f;
    float x2 = roi[3] * 0.0625f;
    float y2 = roi[4] * 0.0625f;
    float bin_h = fmaxf(y2 - y1, 0.0f) * (1.0f / 6.0f);
    float bin_w = fmaxf(x2 - x1, 0.0f) * (1.0f / 6.0f);
    int ph = tid / AWW;
    int pw = tid - ph * AWW;
    float h = y1 + (float)ph * bin_h;
    float w = x1 + (float)pw * bin_w;
    bool valid = (h >= 0.0f) && (h < (float)HH) && (w >= 0.0f) && (w < (float)WW);
    int h0 = min(max((int)floorf(h), 0), HH - 2);
    int w0 = min(max((int)floorf(w), 0), WW - 2);
    float lh = h - (float)h0;   // may exceed 1 near edge (matches reference)
    float lw = w - (float)w0;
    float w00 = (1.0f - lh) * (1.0f - lw);
    float w01 = (1.0f - lh) * lw;
    float w10 = lh * (1.0f - lw);
    float w11 = lh * lw;
    if (!valid) { w00 = 0.0f; w01 = 0.0f; w10 = 0.0f; w11 = 0.0f; }
    s_poff[tid] = (h0 * WW + w0) * CC;
    s_w[0][tid] = w00; s_w[1][tid] = w01; s_w[2][tid] = w10; s_w[3][tid] = w11;
    if (tid == 0) s_base = (int)bf * (HH * WW * CC);
  }
  __syncthreads();   // the ONLY block-wide barrier

  // ---- phase 1: wave wv gathers its 16 channels for all 49 samples ----
  // lane: qq = lane&3 (channel quad within wave), ss = lane>>2 (sample mod 16)
  const int qq = lane & 3;
  const int ss = lane >> 2;
  const float* fb = fT + s_base + c0 + wv * WCH + (qq << 2);
  float* s_mine = s_res + (wv * WCH) * RSTRIDE;   // wave-private [16][53]

#pragma unroll
  for (int it = 0; it < 4; ++it) {
    int s = it * 16 + ss;
    if (s < NS) {
      const float* p = fb + s_poff[s];
      v4f v00 = *(const v4f*)(p);
      v4f v01 = *(const v4f*)(p + CC);
      v4f v10 = *(const v4f*)(p + WW * CC);
      v4f v11 = *(const v4f*)(p + WW * CC + CC);
      v4f r = v00 * s_w[0][s] + v01 * s_w[1][s] + v10 * s_w[2][s] + v11 * s_w[3][s];
      int base = (qq << 2) * RSTRIDE + s;          // local rows 4qq..4qq+3
      s_mine[base]               = r.x;
      s_mine[base + RSTRIDE]     = r.y;
      s_mine[base + 2 * RSTRIDE] = r.z;
      s_mine[base + 3 * RSTRIDE] = r.w;
      // dup samples 0..2 into previous row's tail (stays wave-internal:
      // for local row 0 (qq==0,x) the predecessor belongs to no vec4 of
      // this wave's range — wave ranges end exactly at channel boundaries)
      if (s < 3) {
        int dbase = base - RSTRIDE + 49;
        if (qq > 0) s_mine[dbase] = r.x;           // row 4qq-1 <- ch 4qq
        s_mine[dbase + RSTRIDE]     = r.y;
        s_mine[dbase + 2 * RSTRIDE] = r.z;
        s_mine[dbase + 3 * RSTRIDE] = r.w;
      }
    }
  }
  // no barrier: this wave's reads only touch its own region (compiler
  // orders same-wave ds ops via lgkmcnt)

  // ---- phase 2: wave stores its contiguous (16ch x 49) output slice ----
  v4f* ob = (v4f*)(out + (size_t)n * ELEMS_PER_ROI + (size_t)(c0 + wv * WCH) * NS);
#pragma unroll
  for (int it = 0; it < 4; ++it) {
    int i = it * 64 + lane;              // vec4 index within wave slice
    if (i < VEC4_PER_WAVE) {
      int f0 = i * 4;
      int cl = f0 / NS;                  // local channel 0..15 (magic-multiply)
      const v4f val = *(const v4f*)(s_mine + f0 + 4 * cl);  // cl*53 + s = f0+4cl
      __builtin_nontemporal_store(val, &ob[i]);
    }
  }
}

// ---------------- fallback (no ws) ----------------
__global__ __launch_bounds__(256) void roialign_fallback_kernel(
    const float* __restrict__ features,
    const float* __restrict__ rois,
    float* __restrict__ out) {
  const int n   = blockIdx.x;
  const int tid = threadIdx.x;
  __shared__ int   s_off[NS];
  __shared__ float s_w00[NS], s_w01[NS], s_w10[NS], s_w11[NS];
  __shared__ int   s_base;
  if (tid < NS) {
    const float* roi = rois + n * 5;
    float bf = roi[0];
    float x1 = roi[1] * 0.0625f, y1 = roi[2] * 0.0625f;
    float x2 = roi[3] * 0.0625f, y2 = roi[4] * 0.0625f;
    float bin_h = fmaxf(y2 - y1, 0.0f) * (1.0f / 6.0f);
    float bin_w = fmaxf(x2 - x1, 0.0f) * (1.0f / 6.0f);
    int ph = tid / AWW, pw = tid - ph * AWW;
    float h = y1 + (float)ph * bin_h, w = x1 + (float)pw * bin_w;
    bool valid = (h >= 0.0f) && (h < (float)HH) && (w >= 0.0f) && (w < (float)WW);
    int h0 = min(max((int)floorf(h), 0), HH - 2);
    int w0 = min(max((int)floorf(w), 0), WW - 2);
    float lh = h - (float)h0, lw = w - (float)w0;
    float w00 = (1.0f - lh) * (1.0f - lw), w01 = (1.0f - lh) * lw;
    float w10 = lh * (1.0f - lw), w11 = lh * lw;
    if (!valid) { w00 = w01 = w10 = w11 = 0.0f; }
    s_off[tid] = h0 * WW + w0;
    s_w00[tid] = w00; s_w01[tid] = w01; s_w10[tid] = w10; s_w11[tid] = w11;
    if (tid == 0) s_base = (int)bf * (CC * HH * WW);
  }
  __syncthreads();
  const float* fb = features + s_base;
  v4f* ob = (v4f*)(out + (size_t)n * ELEMS_PER_ROI);
  for (int i = tid; i < ELEMS_PER_ROI / 4; i += 256) {
    int f0 = i * 4;
    float r[4];
#pragma unroll
    for (int j = 0; j < 4; ++j) {
      int f = f0 + j;
      int c = f / NS;
      int s = f - c * NS;
      int off = s_off[s];
      const float* p = fb + (c << 12) + off;
      r[j] = p[0] * s_w00[s] + p[1] * s_w01[s] + p[WW] * s_w10[s] + p[WW + 1] * s_w11[s];
    }
    v4f val = {r[0], r[1], r[2], r[3]};
    __builtin_nontemporal_store(val, &ob[i]);
  }
}

extern "C" void kernel_launch(void* const* d_in, const int* in_sizes, int n_in,
                              void* d_out, int out_size, void* d_ws, size_t ws_size,
                              hipStream_t stream) {
  const float* features = (const float*)d_in[0];
  const float* rois     = (const float*)d_in[1];
  float* out            = (float*)d_out;
  int N = in_sizes[1] / 5;   // 8000

  if (ws_size >= (size_t)FT_ELEMS * sizeof(float)) {
    float* fT = (float*)d_ws;
    transpose_tiled<<<2 * 4 * 64, 256, 0, stream>>>(features, fT);
    roialign_t_kernel<<<N * NCHUNK, 256, 0, stream>>>(fT, rois, out);
  } else {
    roialign_fallback_kernel<<<N, 256, 0, stream>>>(features, rois, out);
  }
}

// Round 12
// 85.315 us; speedup vs baseline: 1.1594x; 1.1594x over previous
//
#include <hip/hip_runtime.h>

#define AHH 7
#define AWW 7
#define NS 49            // AH*AW
#define CC 256
#define HH 64
#define WW 64
#define CCH 64                            // channels per block chunk
#define NCHUNK (CC / CCH)                 // 4 blocks per roi
#define ELEMS_PER_ROI (CC * NS)           // 12544
#define ELEMS_PER_CHUNK (CCH * NS)        // 3136
#define VEC4_PER_CHUNK (ELEMS_PER_CHUNK / 4)  // 784
#define RSTRIDE 53                        // LDS row stride (words): ≡1 mod 4
#define FT_ELEMS (2 * HH * WW * CC)       // 8 MiB
#define TS 64                             // transpose tile

typedef float v4f __attribute__((ext_vector_type(4)));

// ---------------- tiled transpose (B,C,HW) -> (B,HW,C) ----------------
__global__ __launch_bounds__(256) void transpose_tiled(
    const float* __restrict__ A, float* __restrict__ AT) {
  const int bid = blockIdx.x;            // 512 blocks
  const int st  = bid & 63;              // spatial tile (4096/64)
  const int ct  = (bid >> 6) & 3;        // channel tile (256/64)
  const int b   = bid >> 8;
  const int tid = threadIdx.x;

  __shared__ float tile[TS][TS + 1];

  const float* Ab  = A  + (size_t)b * CC * HH * WW;
  float*       ATb = AT + (size_t)b * HH * WW * CC;

  {
    const int col = tid & 63;
    const int r0  = tid >> 6;            // 0..3
#pragma unroll
    for (int k = 0; k < 16; ++k) {
      int r = r0 + (k << 2);
      // lanes: col contiguous -> 256B coalesced read
      tile[r][col] = Ab[(size_t)(ct * TS + r) * (HH * WW) + st * TS + col];
    }
  }
  __syncthreads();
  {
    const int col4 = (tid & 15) << 2;    // 4 consecutive channels
    const int rr   = tid >> 4;           // 0..15
#pragma unroll
    for (int k = 0; k < 4; ++k) {
      int r = rr + (k << 4);
      // banks (4a+b+r)%32 -> 2-way (free); 16 threads x 16B = 256B contiguous store
      v4f val = {tile[col4][r], tile[col4 + 1][r], tile[col4 + 2][r], tile[col4 + 3][r]};
      *(v4f*)(ATb + (size_t)(st * TS + r) * CC + ct * TS + col4) = val;
    }
  }
}

// ---------------- main: 4 blocks per roi, 64 channels each ----------------
__global__ __launch_bounds__(256) void roialign_t_kernel(
    const float* __restrict__ fT,
    const float* __restrict__ rois,
    float* __restrict__ out) {
  const int bid   = blockIdx.x;
  const int n     = bid >> 2;            // roi index
  const int chunk = bid & 3;             // channel chunk 0..3
  const int c0    = chunk * CCH;
  const int tid   = threadIdx.x;

  __shared__ float s_w[4][NS];
  __shared__ int   s_poff[NS];           // (h0*W + w0) * C
  __shared__ int   s_base;               // b * H*W*C
  __shared__ float s_res[CCH * RSTRIDE]; // 13.25 KB, channel-major rows

  if (tid < NS) {
    const float* roi = rois + n * 5;
    float bf = roi[0];
    float x1 = roi[1] * 0.0625f;
    float y1 = roi[2] * 0.0625f;
    float x2 = roi[3] * 0.0625f;
    float y2 = roi[4] * 0.0625f;
    float bin_h = fmaxf(y2 - y1, 0.0f) * (1.0f / 6.0f);
    float bin_w = fmaxf(x2 - x1, 0.0f) * (1.0f / 6.0f);
    int ph = tid / AWW;
    int pw = tid - ph * AWW;
    float h = y1 + (float)ph * bin_h;
    float w = x1 + (float)pw * bin_w;
    bool valid = (h >= 0.0f) && (h < (float)HH) && (w >= 0.0f) && (w < (float)WW);
    int h0 = min(max((int)floorf(h), 0), HH - 2);
    int w0 = min(max((int)floorf(w), 0), WW - 2);
    float lh = h - (float)h0;   // may exceed 1 near edge (matches reference)
    float lw = w - (float)w0;
    float w00 = (1.0f - lh) * (1.0f - lw);
    float w01 = (1.0f - lh) * lw;
    float w10 = lh * (1.0f - lw);
    float w11 = lh * lw;
    if (!valid) { w00 = 0.0f; w01 = 0.0f; w10 = 0.0f; w11 = 0.0f; }
    s_poff[tid] = (h0 * WW + w0) * CC;
    s_w[0][tid] = w00; s_w[1][tid] = w01; s_w[2][tid] = w10; s_w[3][tid] = w11;
    if (tid == 0) s_base = (int)bf * (HH * WW * CC);
  }
  __syncthreads();

  // ---- phase 1: gather. 16 lanes per sample, 4 channels per lane ----
  const float* fb = fT + s_base + c0;

#pragma unroll
  for (int it = 0; it < 4; ++it) {
    int wk = it * 256 + tid;
    int s  = wk >> 4;
    if (s < NS) {
      int q  = wk & 15;
      const float* p = fb + s_poff[s] + (q << 2);
      v4f v00 = *(const v4f*)(p);
      v4f v01 = *(const v4f*)(p + CC);
      v4f v10 = *(const v4f*)(p + WW * CC);
      v4f v11 = *(const v4f*)(p + WW * CC + CC);
      v4f r = v00 * s_w[0][s] + v01 * s_w[1][s] + v10 * s_w[2][s] + v11 * s_w[3][s];
      int base = (q << 2) * RSTRIDE + s;
      s_res[base]               = r.x;
      s_res[base + RSTRIDE]     = r.y;
      s_res[base + 2 * RSTRIDE] = r.z;
      s_res[base + 3 * RSTRIDE] = r.w;
      // duplicate samples 0..2 into tail of previous row so every output
      // vec4 is one aligned ds_read_b128
      if (s < 3) {
        int dbase = base - RSTRIDE + 49;
        if (q > 0) s_res[dbase] = r.x;
        s_res[dbase + RSTRIDE]     = r.y;
        s_res[dbase + 2 * RSTRIDE] = r.z;
        s_res[dbase + 3 * RSTRIDE] = r.w;
      }
    }
  }
  __syncthreads();

  // ---- phase 2: one aligned ds_read_b128 + one NT dwordx4 store per item ----
  // nt confirmed by R7 (86.2) vs R9 (97.2) A/B: write stream must bypass L2.
  v4f* ob = (v4f*)(out + (size_t)n * ELEMS_PER_ROI + (size_t)c0 * NS);
#pragma unroll
  for (int it = 0; it < 4; ++it) {
    int i = it * 256 + tid;
    if (i < VEC4_PER_CHUNK) {
      int f0 = i * 4;
      int cl = f0 / NS;                  // magic-multiply
      const v4f val = *(const v4f*)(s_res + f0 + 4 * cl);
      __builtin_nontemporal_store(val, &ob[i]);
    }
  }
}

// ---------------- fallback (no ws) ----------------
__global__ __launch_bounds__(256) void roialign_fallback_kernel(
    const float* __restrict__ features,
    const float* __restrict__ rois,
    float* __restrict__ out) {
  const int n   = blockIdx.x;
  const int tid = threadIdx.x;
  __shared__ int   s_off[NS];
  __shared__ float s_w00[NS], s_w01[NS], s_w10[NS], s_w11[NS];
  __shared__ int   s_base;
  if (tid < NS) {
    const float* roi = rois + n * 5;
    float bf = roi[0];
    float x1 = roi[1] * 0.0625f, y1 = roi[2] * 0.0625f;
    float x2 = roi[3] * 0.0625f, y2 = roi[4] * 0.0625f;
    float bin_h = fmaxf(y2 - y1, 0.0f) * (1.0f / 6.0f);
    float bin_w = fmaxf(x2 - x1, 0.0f) * (1.0f / 6.0f);
    int ph = tid / AWW, pw = tid - ph * AWW;
    float h = y1 + (float)ph * bin_h, w = x1 + (float)pw * bin_w;
    bool valid = (h >= 0.0f) && (h < (float)HH) && (w >= 0.0f) && (w < (float)WW);
    int h0 = min(max((int)floorf(h), 0), HH - 2);
    int w0 = min(max((int)floorf(w), 0), WW - 2);
    float lh = h - (float)h0, lw = w - (float)w0;
    float w00 = (1.0f - lh) * (1.0f - lw), w01 = (1.0f - lh) * lw;
    float w10 = lh * (1.0f - lw), w11 = lh * lw;
    if (!valid) { w00 = w01 = w10 = w11 = 0.0f; }
    s_off[tid] = h0 * WW + w0;
    s_w00[tid] = w00; s_w01[tid] = w01; s_w10[tid] = w10; s_w11[tid] = w11;
    if (tid == 0) s_base = (int)bf * (CC * HH * WW);
  }
  __syncthreads();
  const float* fb = features + s_base;
  v4f* ob = (v4f*)(out + (size_t)n * ELEMS_PER_ROI);
  for (int i = tid; i < ELEMS_PER_ROI / 4; i += 256) {
    int f0 = i * 4;
    float r[4];
#pragma unroll
    for (int j = 0; j < 4; ++j) {
      int f = f0 + j;
      int c = f / NS;
      int s = f - c * NS;
      int off = s_off[s];
      const float* p = fb + (c << 12) + off;
      r[j] = p[0] * s_w00[s] + p[1] * s_w01[s] + p[WW] * s_w10[s] + p[WW + 1] * s_w11[s];
    }
    v4f val = {r[0], r[1], r[2], r[3]};
    __builtin_nontemporal_store(val, &ob[i]);
  }
}

extern "C" void kernel_launch(void* const* d_in, const int* in_sizes, int n_in,
                              void* d_out, int out_size, void* d_ws, size_t ws_size,
                              hipStream_t stream) {
  const float* features = (const float*)d_in[0];
  const float* rois     = (const float*)d_in[1];
  float* out            = (float*)d_out;
  int N = in_sizes[1] / 5;   // 8000

  if (ws_size >= (size_t)FT_ELEMS * sizeof(float)) {
    float* fT = (float*)d_ws;
    transpose_tiled<<<2 * 4 * 64, 256, 0, stream>>>(features, fT);
    roialign_t_kernel<<<N * NCHUNK, 256, 0, stream>>>(fT, rois, out);
  } else {
    roialign_fallback_kernel<<<N, 256, 0, stream>>>(features, rois, out);
  }
}